// Round 9
// baseline (325.969 us; speedup 1.0000x reference)
//
#include <hip/hip_runtime.h>

#define HID 128
#define NG 512
#define NC 10
#define BSH 9                 // bucket = dst >> BSH (512 nodes per bucket)
#define BSZ (1 << BSH)
#define TILE 4096             // edges per k_part1/k_bhist block
#define NOEDGE 0xFFFFFFFFu

typedef unsigned int u32;
typedef unsigned short u16;
typedef __attribute__((ext_vector_type(8))) short short8;
typedef __attribute__((ext_vector_type(4))) float f32x4;

static __device__ __forceinline__ int gtid() {
    return blockIdx.x * blockDim.x + threadIdx.x;
}

// bf16 helpers (RNE pack, exact unpack)
static __device__ __forceinline__ u16 f2bf(float f) {
    u32 u = __float_as_uint(f);
    u32 r = u + 0x7fffu + ((u >> 16) & 1u);
    return (u16)(r >> 16);
}
static __device__ __forceinline__ float bf2f(u32 s) {
    return __uint_as_float(s << 16);
}
static __device__ __forceinline__ void bf8_unpack(uint4 u, float* f) {
    f[0] = bf2f(u.x & 0xffffu); f[1] = bf2f(u.x >> 16);
    f[2] = bf2f(u.y & 0xffffu); f[3] = bf2f(u.y >> 16);
    f[4] = bf2f(u.z & 0xffffu); f[5] = bf2f(u.z >> 16);
    f[6] = bf2f(u.w & 0xffffu); f[7] = bf2f(u.w >> 16);
}

// ---------- bucket-level histogram ----------
__global__ __launch_bounds__(256) void k_bhist(const int* __restrict__ dst,
                                               int* __restrict__ bcnt, int E, int NB) {
    __shared__ int cnt[256];
    int t = threadIdx.x;
    int e0 = blockIdx.x * TILE;
    for (int i = t; i < NB; i += 256) cnt[i] = 0;
    __syncthreads();
#pragma unroll
    for (int k = 0; k < 16; ++k) {
        int e = e0 + k * 256 + t;
        if (e < E) atomicAdd(&cnt[dst[e] >> BSH], 1);
    }
    __syncthreads();
    for (int i = t; i < NB; i += 256)
        if (cnt[i] > 0) atomicAdd(&bcnt[i], cnt[i]);
}

// exclusive scan of bucket counts -> bbase[NB+1]; init bcur
__global__ __launch_bounds__(256) void k_bscan(const int* __restrict__ bcnt,
                                               int* __restrict__ bbase,
                                               int* __restrict__ bcur, int NB, int E) {
    __shared__ int s[256];
    int t = threadIdx.x;
    int own = (t < NB) ? bcnt[t] : 0;
    s[t] = own;
    __syncthreads();
    for (int off = 1; off < 256; off <<= 1) {
        int v = (t >= off) ? s[t - off] : 0;
        __syncthreads();
        s[t] += v;
        __syncthreads();
    }
    if (t < NB) {
        int b = s[t] - own;
        bbase[t] = b;
        bcur[t] = b;
    }
    if (t == 0) bbase[NB] = E;
}

// pass 1: coarse partition; payload u32 = (src<<BSH)|dst_local
__global__ __launch_bounds__(256) void k_part1(const int* __restrict__ src,
                                               const int* __restrict__ dst,
                                               int* __restrict__ bcur,
                                               u32* __restrict__ tmp, int E, int NB) {
    __shared__ int cnt[256];
    __shared__ int base[256];
    int t = threadIdx.x;
    int e0 = blockIdx.x * TILE;
    for (int i = t; i < NB; i += 256) cnt[i] = 0;
    __syncthreads();
    u32 p_[16];
    int b_[16];
#pragma unroll
    for (int k = 0; k < 16; ++k) {
        int e = e0 + k * 256 + t;
        if (e < E) {
            int d = dst[e];
            p_[k] = ((u32)src[e] << BSH) | (u32)(d & (BSZ - 1));
            b_[k] = d >> BSH;
            atomicAdd(&cnt[b_[k]], 1);
        } else {
            b_[k] = -1;
        }
    }
    __syncthreads();
    for (int i = t; i < NB; i += 256) {
        if (cnt[i] > 0) base[i] = atomicAdd(&bcur[i], cnt[i]);
        cnt[i] = 0;
    }
    __syncthreads();
#pragma unroll
    for (int k = 0; k < 16; ++k) {
        if (b_[k] >= 0) {
            int pos = base[b_[k]] + atomicAdd(&cnt[b_[k]], 1);
            tmp[pos] = p_[k];
        }
    }
}

// pass 2: per-bucket degree + scan -> rowptr/dinv, counting sort -> packed
__global__ __launch_bounds__(512) void k_part2(const int* __restrict__ bbase,
                                               const u32* __restrict__ tmp,
                                               u32* __restrict__ packed,
                                               int* __restrict__ rowptr,
                                               float* __restrict__ dinv,
                                               int N, int NB) {
    __shared__ int cnt[BSZ];
    __shared__ int scn[BSZ];
    __shared__ int cur[BSZ];
    int b = blockIdx.x;
    int v0 = b << BSH;
    int nv = N - v0; if (nv > BSZ) nv = BSZ;
    int t = threadIdx.x;
    int e0 = bbase[b], e1 = bbase[b + 1];

    cnt[t] = 0;
    __syncthreads();
    for (int e = e0 + t; e < e1; e += 512)
        atomicAdd(&cnt[tmp[e] & (BSZ - 1)], 1);
    __syncthreads();
    int own = cnt[t];
    scn[t] = own;
    __syncthreads();
    for (int off = 1; off < BSZ; off <<= 1) {
        int v = (t >= off) ? scn[t - off] : 0;
        __syncthreads();
        scn[t] += v;
        __syncthreads();
    }
    int start = e0 + scn[t] - own;   // exclusive
    cur[t] = start;
    if (t < nv) {
        rowptr[v0 + t] = start;
        dinv[v0 + t] = rsqrtf(1.0f + (float)own);
    }
    if (b == NB - 1 && t == 0) rowptr[N] = e1;
    __syncthreads();
    for (int e = e0 + t; e < e1; e += 512) {
        u32 p = tmp[e];
        int pos = atomicAdd(&cur[p & (BSZ - 1)], 1);
        packed[pos] = p >> BSH;   // src
    }
}

// ---------- layer0+GEMM1 fusion tables ----------
// breakpoints t_d = -b0[d]/W0[d]; sort -> ts + sidx (odd-even transposition, 1 block)
__global__ __launch_bounds__(128) void k_sort(const float* __restrict__ W0,
                                              const float* __restrict__ b0,
                                              float* __restrict__ ts,
                                              int* __restrict__ sidx) {
    __shared__ float t[HID];
    __shared__ int ix[HID];
    int i = threadIdx.x;
    float w = W0[i];
    t[i] = (w != 0.0f) ? (-b0[i] / w) : 3.0e38f;   // W0==0: park at +inf (handled by sign in table)
    ix[i] = i;
    __syncthreads();
    for (int ph = 0; ph < HID; ++ph) {
        int j = 2 * i + (ph & 1);
        if (j + 1 < HID) {
            if (t[j] > t[j + 1]) {
                float tv = t[j]; t[j] = t[j + 1]; t[j + 1] = tv;
                int iv = ix[j]; ix[j] = ix[j + 1]; ix[j + 1] = iv;
            }
        }
        __syncthreads();
    }
    ts[i] = t[i];
    sidx[i] = ix[i];
}

// table: for interval r (0..128), A[r,:] = sum_active W0[d]*W1[d,:], B[r,:] = sum_active b0[d]*W1[d,:]
// active(d at sorted pos p): W0>0 -> p<r ; W0<0 -> p>=r ; W0==0 -> b0>0
__global__ __launch_bounds__(128) void k_tab(const float* __restrict__ W0,
                                             const float* __restrict__ b0,
                                             const float* __restrict__ W1,
                                             const int* __restrict__ sidx,
                                             float* __restrict__ A,
                                             float* __restrict__ Bt) {
    __shared__ float w0s[HID], b0s[HID];
    __shared__ int ds[HID];
    int r = blockIdx.x;            // 0..128
    int j = threadIdx.x;           // output dim
    ds[j] = sidx[j];
    w0s[j] = W0[ds[j]];
    b0s[j] = b0[ds[j]];
    __syncthreads();
    float a = 0.0f, b = 0.0f;
    for (int p = 0; p < HID; ++p) {
        int d = ds[p];
        float w0 = w0s[p];
        bool act = (w0 != 0.0f) ? ((w0 > 0.0f) ? (p < r) : (p >= r)) : (b0s[p] > 0.0f);
        if (act) {
            float w1 = W1[d * HID + j];
            a = fmaf(w0, w1, a);
            b = fmaf(b0s[p], w1, b);
        }
    }
    A[r * HID + j] = a;
    Bt[r * HID + j] = b;
}

// fused layer0 + GEMM1: s_v reduce -> binary search -> q1 = dinv_v*(A[r]*s + B[r])
__global__ __launch_bounds__(256) void k_l01(const int* __restrict__ rowptr,
                                             const u32* __restrict__ packed,
                                             const float* __restrict__ dinv,
                                             const float* __restrict__ ts,
                                             const float* __restrict__ A,
                                             const float* __restrict__ Bt,
                                             u16* __restrict__ q, int N) {
    __shared__ float tls[HID];
    if (threadIdx.x < HID) tls[threadIdx.x] = ts[threadIdx.x];
    __syncthreads();
    int lane = threadIdx.x & 31;
    int v = (blockIdx.x * 256 + threadIdx.x) >> 5;
    if (v >= N) return;
    int r0 = rowptr[v], r1 = rowptr[v + 1];
    float s = 0.0f;
    for (int j = r0 + lane; j < r1; j += 32) s += dinv[packed[j]];
#pragma unroll
    for (int off = 16; off > 0; off >>= 1) s += __shfl_xor(s, off, 32);
    float di = dinv[v];
    s = di * (di + s);
    // r = count of ts strictly < s  (boundaries contribute relu(0)=0 either way)
    int lo = 0, hi = HID;
    while (lo < hi) {
        int mid = (lo + hi) >> 1;
        if (tls[mid] < s) lo = mid + 1; else hi = mid;
    }
    int r = lo;
    int d0 = lane * 4;
    float4 av = *(const float4*)&A[r * HID + d0];
    float4 bv = *(const float4*)&Bt[r * HID + d0];
    float q0 = di * fmaf(av.x, s, bv.x);
    float q1 = di * fmaf(av.y, s, bv.y);
    float q2 = di * fmaf(av.z, s, bv.z);
    float q3 = di * fmaf(av.w, s, bv.w);
    uint2 o;
    o.x = (u32)f2bf(q0) | ((u32)f2bf(q1) << 16);
    o.y = (u32)f2bf(q2) | ((u32)f2bf(q3) << 16);
    *(uint2*)&q[(size_t)v * HID + d0] = o;
}

// ---------- W -> bf16 transposed + XOR-swizzled (one-shot) ----------
__global__ __launch_bounds__(256) void k_wt(const float* __restrict__ W,
                                            u16* __restrict__ Wt) {
    int t = gtid();               // 0..2047
    if (t >= 2048) return;
    int n = t >> 4;               // output row (col of W)
    int j = t & 15;               // 16B block index along k
    int js = j ^ (n & 7);
    u32 w0 = (u32)f2bf(W[(j * 8 + 0) * HID + n]) | ((u32)f2bf(W[(j * 8 + 1) * HID + n]) << 16);
    u32 w1 = (u32)f2bf(W[(j * 8 + 2) * HID + n]) | ((u32)f2bf(W[(j * 8 + 3) * HID + n]) << 16);
    u32 w2 = (u32)f2bf(W[(j * 8 + 4) * HID + n]) | ((u32)f2bf(W[(j * 8 + 5) * HID + n]) << 16);
    u32 w3 = (u32)f2bf(W[(j * 8 + 6) * HID + n]) | ((u32)f2bf(W[(j * 8 + 7) * HID + n]) << 16);
    uint4 o = make_uint4(w0, w1, w2, w3);
    *(uint4*)&Wt[(size_t)n * HID + js * 8] = o;
}

// ---------- MFMA GEMM with dinv-premultiplied output ----------
__global__ __launch_bounds__(256) void k_gemm(const u16* __restrict__ x,
                                              const u16* __restrict__ Wt,
                                              const float* __restrict__ dinv,
                                              u16* __restrict__ q, int nrows) {
    __shared__ u16 Wl[HID * HID];  // 32 KiB
    int tid = threadIdx.x;
    for (int i = tid; i < 2048; i += 256)
        *(uint4*)&Wl[i * 8] = *(const uint4*)&Wt[i * 8];

    int w = tid >> 6;
    int l = tid & 63;
    int R0 = blockIdx.x * 64 + w * 16;
    int arow = R0 + (l & 15);
    int koff = (l >> 4) * 8;

    short8 a[4];
#pragma unroll
    for (int kb = 0; kb < 4; ++kb) {
        if (arow < nrows)
            a[kb] = *(const short8*)&x[(size_t)arow * HID + kb * 32 + koff];
        else
            a[kb] = (short8)0;
    }
    __syncthreads();

    int colbase = l & 15;
    int rowq = (l >> 4) * 4;
    float dv[4];
#pragma unroll
    for (int i = 0; i < 4; ++i) {
        int orow = R0 + rowq + i;
        dv[i] = (orow < nrows) ? dinv[orow] : 0.0f;
    }
#pragma unroll
    for (int cb = 0; cb < 8; ++cb) {
        f32x4 acc = {0.0f, 0.0f, 0.0f, 0.0f};
        int wrow = cb * 16 + (l & 15);
#pragma unroll
        for (int kb = 0; kb < 4; ++kb) {
            int j = (kb * 4 + (l >> 4)) ^ (wrow & 7);
            short8 b = *(const short8*)&Wl[wrow * HID + j * 8];
            acc = __builtin_amdgcn_mfma_f32_16x16x32_bf16(a[kb], b, acc, 0, 0, 0);
        }
#pragma unroll
        for (int i = 0; i < 4; ++i) {
            int orow = R0 + rowq + i;
            if (orow < nrows)
                q[(size_t)orow * HID + cb * 16 + colbase] = f2bf(acc[i] * dv[i]);
        }
    }
}

// ---------- fused aggregation: 64-lane wave per node, 4 edges in parallel, 2-deep ----------
// y[v,:] = relu( dinv[v]*(q[v,:] + sum_e q[src_e,:]) + b )
__global__ __launch_bounds__(256) void k_aggr(const u32* __restrict__ packed,
                                              const int* __restrict__ rowptr,
                                              const u16* __restrict__ q,
                                              const float* __restrict__ dinv,
                                              const float* __restrict__ b,
                                              u16* __restrict__ y, int N) {
    int lane = threadIdx.x & 63;
    int v = (blockIdx.x * 256 + threadIdx.x) >> 6;
    if (v >= N) return;
    int r0 = rowptr[v], r1 = rowptr[v + 1];
    int q4 = lane >> 4;              // quarter 0..3
    int d8 = (lane & 15) * 8;

    float acc[8];
    if (q4 == 0) {
        uint4 qv = *(const uint4*)&q[(size_t)v * HID + d8];
        bf8_unpack(qv, acc);
    } else {
#pragma unroll
        for (int j = 0; j < 8; ++j) acc[j] = 0.0f;
    }

    for (int base = r0; base < r1; base += 64) {
        int idx = base + lane;
        u32 e = (idx < r1) ? packed[idx] : NOEDGE;
        int m = r1 - base; if (m > 64) m = 64;
        int iters = (m + 3) >> 2;    // steps of 4 edges
        int k = 0;
        for (; k + 2 <= iters; k += 2) {
            u32 s0 = __shfl(e, 4 * k + q4, 64);
            u32 s1 = __shfl(e, 4 * k + 4 + q4, 64);
            uint4 h0 = make_uint4(0, 0, 0, 0);
            uint4 h1 = make_uint4(0, 0, 0, 0);
            if (s0 != NOEDGE) h0 = *(const uint4*)&q[(size_t)s0 * HID + d8];
            if (s1 != NOEDGE) h1 = *(const uint4*)&q[(size_t)s1 * HID + d8];
            float f0[8], f1[8];
            bf8_unpack(h0, f0);
            bf8_unpack(h1, f1);
#pragma unroll
            for (int j = 0; j < 8; ++j) acc[j] += f0[j] + f1[j];
        }
        if (k < iters) {
            u32 s0 = __shfl(e, 4 * k + q4, 64);
            if (s0 != NOEDGE) {
                uint4 h0 = *(const uint4*)&q[(size_t)s0 * HID + d8];
                float f0[8];
                bf8_unpack(h0, f0);
#pragma unroll
                for (int j = 0; j < 8; ++j) acc[j] += f0[j];
            }
        }
    }
#pragma unroll
    for (int j = 0; j < 8; ++j) {
        acc[j] += __shfl_xor(acc[j], 16, 64);
        acc[j] += __shfl_xor(acc[j], 32, 64);
    }

    if (q4 == 0) {
        float dv = dinv[v];
        float4 b0 = *(const float4*)&b[d8];
        float4 b1 = *(const float4*)&b[d8 + 4];
        float o[8];
        o[0] = fmaxf(fmaf(acc[0], dv, b0.x), 0.0f);
        o[1] = fmaxf(fmaf(acc[1], dv, b0.y), 0.0f);
        o[2] = fmaxf(fmaf(acc[2], dv, b0.z), 0.0f);
        o[3] = fmaxf(fmaf(acc[3], dv, b0.w), 0.0f);
        o[4] = fmaxf(fmaf(acc[4], dv, b1.x), 0.0f);
        o[5] = fmaxf(fmaf(acc[5], dv, b1.y), 0.0f);
        o[6] = fmaxf(fmaf(acc[6], dv, b1.z), 0.0f);
        o[7] = fmaxf(fmaf(acc[7], dv, b1.w), 0.0f);
        uint4 u;
        u.x = (u32)f2bf(o[0]) | ((u32)f2bf(o[1]) << 16);
        u.y = (u32)f2bf(o[2]) | ((u32)f2bf(o[3]) << 16);
        u.z = (u32)f2bf(o[4]) | ((u32)f2bf(o[5]) << 16);
        u.w = (u32)f2bf(o[6]) | ((u32)f2bf(o[7]) << 16);
        *(uint4*)&y[(size_t)v * HID + d8] = u;
    }
}

// ---------- pooling (16 lanes x 8 dims per node) ----------
__global__ __launch_bounds__(256) void k_pool(const u16* __restrict__ x,
                                              const int* __restrict__ batch,
                                              float* __restrict__ pooled,
                                              float* __restrict__ cntg, int N) {
    const int K = 32;
    int grp = threadIdx.x >> 4;
    int lane16 = threadIdx.x & 15;
    int d8 = lane16 * 8;
    int chunk = blockIdx.x * 16 + grp;
    int v0 = chunk * K;
    if (v0 >= N) return;
    int vend = v0 + K; if (vend > N) vend = N;
    int g = batch[v0];
    float acc[8] = {0, 0, 0, 0, 0, 0, 0, 0};
    float c = 0.0f;
    for (int v = v0; v < vend; ++v) {
        int gv = batch[v];
        if (gv != g) {
#pragma unroll
            for (int j = 0; j < 8; ++j) atomicAdd(&pooled[g * HID + d8 + j], acc[j]);
            if (lane16 == 0) atomicAdd(&cntg[g], c);
#pragma unroll
            for (int j = 0; j < 8; ++j) acc[j] = 0.0f;
            c = 0.0f; g = gv;
        }
        uint4 u = *(const uint4*)&x[(size_t)v * HID + d8];
        float f[8];
        bf8_unpack(u, f);
#pragma unroll
        for (int j = 0; j < 8; ++j) acc[j] += f[j];
        c += 1.0f;
    }
#pragma unroll
    for (int j = 0; j < 8; ++j) atomicAdd(&pooled[g * HID + d8 + j], acc[j]);
    if (lane16 == 0) atomicAdd(&cntg[g], c);
}

__global__ void k_head(const float* __restrict__ pooled, const float* __restrict__ cnt,
                       const float* __restrict__ Wp, const float* __restrict__ bp,
                       float* __restrict__ out) {
    int g = gtid();
    if (g >= NG) return;
    float inv = 1.0f / fmaxf(cnt[g], 1.0f);
    float l[NC];
#pragma unroll
    for (int c = 0; c < NC; ++c) l[c] = bp[c];
    for (int d = 0; d < HID; ++d) {
        float pv = pooled[g * HID + d] * inv;
#pragma unroll
        for (int c = 0; c < NC; ++c) l[c] = fmaf(pv, Wp[d * NC + c], l[c]);
    }
    float m = l[0];
#pragma unroll
    for (int c = 1; c < NC; ++c) m = fmaxf(m, l[c]);
    float s = 0.0f;
#pragma unroll
    for (int c = 0; c < NC; ++c) s += expf(l[c] - m);
    float ls = logf(s) + m;
#pragma unroll
    for (int c = 0; c < NC; ++c) out[g * NC + c] = l[c] - ls;
}

extern "C" void kernel_launch(void* const* d_in, const int* in_sizes, int n_in,
                              void* d_out, int out_size, void* d_ws, size_t ws_size,
                              hipStream_t stream) {
    const int* ei    = (const int*)d_in[0];
    int E            = in_sizes[0] / 2;
    const int* src   = ei;
    const int* dstp  = ei + E;
    const int* batch = (const int*)d_in[1];
    int N            = in_sizes[1];
    const float* W0  = (const float*)d_in[2];
    const float* b0  = (const float*)d_in[3];
    const float* W1  = (const float*)d_in[4];
    const float* b1  = (const float*)d_in[5];
    const float* W2  = (const float*)d_in[6];
    const float* b2  = (const float*)d_in[7];
    const float* Wp  = (const float*)d_in[8];
    const float* bp  = (const float*)d_in[9];
    float* out       = (float*)d_out;

    // workspace layout
    u16*  xA     = (u16*)d_ws;                    // N*HID bf16
    u16*  xB     = xA + (size_t)N * HID;          // N*HID bf16
    u32*  packed = (u32*)(xB + (size_t)N * HID);  // E u32 (src per CSR slot)
    u32*  tmp    = packed + E;                    // E u32 (bucket-partitioned (src<<9)|dl)
    u16*  Wt2    = (u16*)(tmp + E);               // 128*128 bf16
    float* A     = (float*)(Wt2 + HID * HID);     // 129*128 f
    float* Bt    = A + 129 * HID;                 // 129*128 f
    float* ts    = Bt + 129 * HID;                // 128 f
    int*  sidx   = (int*)(ts + HID);              // 128
    int*  rowptr = sidx + HID;                    // N+1
    int*  bcnt   = rowptr + N + 1;                // 256
    int*  bbase  = bcnt + 256;                    // 257
    int*  bcur   = bbase + 257;                   // 256
    float* dinv  = (float*)(bcur + 256);          // N
    float* pooled= dinv + N;                      // NG*HID
    float* cntg  = pooled + NG * HID;             // NG

    auto cdiv = [](int a, int b) { return (a + b - 1) / b; };
    int NB = cdiv(N, BSZ);                        // 196 buckets

    hipMemsetAsync(bcnt, 0, 256 * sizeof(int), stream);
    hipMemsetAsync(pooled, 0, (NG * HID + NG) * sizeof(float), stream);

    // CSR build
    k_bhist<<<cdiv(E, TILE), 256, 0, stream>>>(dstp, bcnt, E, NB);
    k_bscan<<<1, 256, 0, stream>>>(bcnt, bbase, bcur, NB, E);
    k_part1<<<cdiv(E, TILE), 256, 0, stream>>>(src, dstp, bcur, tmp, E, NB);
    k_part2<<<NB, 512, 0, stream>>>(bbase, tmp, packed, rowptr, dinv, N, NB);

    // layer0+GEMM1 tables & weight prep
    k_sort<<<1, 128, 0, stream>>>(W0, b0, ts, sidx);
    k_tab<<<129, 128, 0, stream>>>(W0, b0, W1, sidx, A, Bt);
    k_wt<<<8, 256, 0, stream>>>(W2, Wt2);

    // fused layer0 + GEMM1: q1 -> xB
    k_l01<<<cdiv(N, 8), 256, 0, stream>>>(rowptr, packed, dinv, ts, A, Bt, xB, N);

    // aggregation layer1 -> xA
    k_aggr<<<cdiv(N, 4), 256, 0, stream>>>(packed, rowptr, xB, dinv, b1, xA, N);

    // layer 2: GEMM + aggregation
    k_gemm<<<cdiv(N, 64), 256, 0, stream>>>(xA, Wt2, dinv, xB, N);
    k_aggr<<<cdiv(N, 4), 256, 0, stream>>>(packed, rowptr, xB, dinv, b2, xA, N);

    // pooling + head
    k_pool<<<cdiv(cdiv(N, 32), 16), 256, 0, stream>>>(xA, batch, pooled, cntg, N);
    k_head<<<2, 256, 0, stream>>>(pooled, cntg, Wp, bp, out);
}

// Round 10
// 282.944 us; speedup vs baseline: 1.1521x; 1.1521x over previous
//
#include <hip/hip_runtime.h>

#define HID 128
#define NG 512
#define NC 10
#define BSH 9                 // bucket = dst >> BSH (512 nodes per bucket)
#define BSZ (1 << BSH)
#define TILE 4096             // edges per k_part1/k_bhist block
#define NOEDGE 0xFFFFFFFFu

typedef unsigned int u32;
typedef unsigned short u16;
typedef __attribute__((ext_vector_type(8))) short short8;
typedef __attribute__((ext_vector_type(4))) float f32x4;

static __device__ __forceinline__ int gtid() {
    return blockIdx.x * blockDim.x + threadIdx.x;
}

// bf16 helpers (RNE pack, exact unpack)
static __device__ __forceinline__ u16 f2bf(float f) {
    u32 u = __float_as_uint(f);
    u32 r = u + 0x7fffu + ((u >> 16) & 1u);
    return (u16)(r >> 16);
}
static __device__ __forceinline__ float bf2f(u32 s) {
    return __uint_as_float(s << 16);
}
static __device__ __forceinline__ void bf8_unpack(uint4 u, float* f) {
    f[0] = bf2f(u.x & 0xffffu); f[1] = bf2f(u.x >> 16);
    f[2] = bf2f(u.y & 0xffffu); f[3] = bf2f(u.y >> 16);
    f[4] = bf2f(u.z & 0xffffu); f[5] = bf2f(u.z >> 16);
    f[6] = bf2f(u.w & 0xffffu); f[7] = bf2f(u.w >> 16);
}

// ---------- bucket-level histogram ----------
__global__ __launch_bounds__(256) void k_bhist(const int* __restrict__ dst,
                                               int* __restrict__ bcnt, int E, int NB) {
    __shared__ int cnt[256];
    int t = threadIdx.x;
    int e0 = blockIdx.x * TILE;
    for (int i = t; i < NB; i += 256) cnt[i] = 0;
    __syncthreads();
#pragma unroll
    for (int k = 0; k < 16; ++k) {
        int e = e0 + k * 256 + t;
        if (e < E) atomicAdd(&cnt[dst[e] >> BSH], 1);
    }
    __syncthreads();
    for (int i = t; i < NB; i += 256)
        if (cnt[i] > 0) atomicAdd(&bcnt[i], cnt[i]);
}

// exclusive scan of bucket counts -> bbase[NB+1]; init bcur
__global__ __launch_bounds__(256) void k_bscan(const int* __restrict__ bcnt,
                                               int* __restrict__ bbase,
                                               int* __restrict__ bcur, int NB, int E) {
    __shared__ int s[256];
    int t = threadIdx.x;
    int own = (t < NB) ? bcnt[t] : 0;
    s[t] = own;
    __syncthreads();
    for (int off = 1; off < 256; off <<= 1) {
        int v = (t >= off) ? s[t - off] : 0;
        __syncthreads();
        s[t] += v;
        __syncthreads();
    }
    if (t < NB) {
        int b = s[t] - own;
        bbase[t] = b;
        bcur[t] = b;
    }
    if (t == 0) bbase[NB] = E;
}

// pass 1: coarse partition; payload u32 = (src<<BSH)|dst_local
__global__ __launch_bounds__(256) void k_part1(const int* __restrict__ src,
                                               const int* __restrict__ dst,
                                               int* __restrict__ bcur,
                                               u32* __restrict__ tmp, int E, int NB) {
    __shared__ int cnt[256];
    __shared__ int base[256];
    int t = threadIdx.x;
    int e0 = blockIdx.x * TILE;
    for (int i = t; i < NB; i += 256) cnt[i] = 0;
    __syncthreads();
    u32 p_[16];
    int b_[16];
#pragma unroll
    for (int k = 0; k < 16; ++k) {
        int e = e0 + k * 256 + t;
        if (e < E) {
            int d = dst[e];
            p_[k] = ((u32)src[e] << BSH) | (u32)(d & (BSZ - 1));
            b_[k] = d >> BSH;
            atomicAdd(&cnt[b_[k]], 1);
        } else {
            b_[k] = -1;
        }
    }
    __syncthreads();
    for (int i = t; i < NB; i += 256) {
        if (cnt[i] > 0) base[i] = atomicAdd(&bcur[i], cnt[i]);
        cnt[i] = 0;
    }
    __syncthreads();
#pragma unroll
    for (int k = 0; k < 16; ++k) {
        if (b_[k] >= 0) {
            int pos = base[b_[k]] + atomicAdd(&cnt[b_[k]], 1);
            tmp[pos] = p_[k];
        }
    }
}

// pass 2: per-bucket degree + scan -> rowptr/dinv, counting sort -> packed
__global__ __launch_bounds__(512) void k_part2(const int* __restrict__ bbase,
                                               const u32* __restrict__ tmp,
                                               u32* __restrict__ packed,
                                               int* __restrict__ rowptr,
                                               float* __restrict__ dinv,
                                               int N, int NB) {
    __shared__ int cnt[BSZ];
    __shared__ int scn[BSZ];
    __shared__ int cur[BSZ];
    int b = blockIdx.x;
    int v0 = b << BSH;
    int nv = N - v0; if (nv > BSZ) nv = BSZ;
    int t = threadIdx.x;
    int e0 = bbase[b], e1 = bbase[b + 1];

    cnt[t] = 0;
    __syncthreads();
    for (int e = e0 + t; e < e1; e += 512)
        atomicAdd(&cnt[tmp[e] & (BSZ - 1)], 1);
    __syncthreads();
    int own = cnt[t];
    scn[t] = own;
    __syncthreads();
    for (int off = 1; off < BSZ; off <<= 1) {
        int v = (t >= off) ? scn[t - off] : 0;
        __syncthreads();
        scn[t] += v;
        __syncthreads();
    }
    int start = e0 + scn[t] - own;   // exclusive
    cur[t] = start;
    if (t < nv) {
        rowptr[v0 + t] = start;
        dinv[v0 + t] = rsqrtf(1.0f + (float)own);
    }
    if (b == NB - 1 && t == 0) rowptr[N] = e1;
    __syncthreads();
    for (int e = e0 + t; e < e1; e += 512) {
        u32 p = tmp[e];
        int pos = atomicAdd(&cur[p & (BSZ - 1)], 1);
        packed[pos] = p >> BSH;   // src
    }
}

// ---------- S[v] = dinv[v]*(dinv[v] + sum_e dinv[src]) ----------
__global__ __launch_bounds__(256) void k_S(const int* __restrict__ rowptr,
                                           const u32* __restrict__ packed,
                                           const float* __restrict__ dinv,
                                           float* __restrict__ S, int N) {
    int lane = threadIdx.x & 31;
    int v = (blockIdx.x * 256 + threadIdx.x) >> 5;
    if (v >= N) return;
    int r0 = rowptr[v], r1 = rowptr[v + 1];
    float s = 0.0f;
    for (int j = r0 + lane; j < r1; j += 32) s += dinv[packed[j]];
#pragma unroll
    for (int off = 16; off > 0; off >>= 1) s += __shfl_xor(s, off, 32);
    if (lane == 0) {
        float di = dinv[v];
        S[v] = di * (di + s);
    }
}

// ---------- W -> bf16 transposed + XOR-swizzled (one-shot) ----------
__global__ __launch_bounds__(256) void k_wt(const float* __restrict__ W,
                                            u16* __restrict__ Wt) {
    int t = gtid();               // 0..2047
    if (t >= 2048) return;
    int n = t >> 4;               // output row (col of W)
    int j = t & 15;               // 16B block index along k
    int js = j ^ (n & 7);
    u32 w0 = (u32)f2bf(W[(j * 8 + 0) * HID + n]) | ((u32)f2bf(W[(j * 8 + 1) * HID + n]) << 16);
    u32 w1 = (u32)f2bf(W[(j * 8 + 2) * HID + n]) | ((u32)f2bf(W[(j * 8 + 3) * HID + n]) << 16);
    u32 w2 = (u32)f2bf(W[(j * 8 + 4) * HID + n]) | ((u32)f2bf(W[(j * 8 + 5) * HID + n]) << 16);
    u32 w3 = (u32)f2bf(W[(j * 8 + 6) * HID + n]) | ((u32)f2bf(W[(j * 8 + 7) * HID + n]) << 16);
    uint4 o = make_uint4(w0, w1, w2, w3);
    *(uint4*)&Wt[(size_t)n * HID + js * 8] = o;
}

// ---------- fused layer0 + MFMA GEMM1 ----------
// A-fragment computed in-register: x[row,k] = relu(S[row]*W0[k]+b0[k])
// q[row,:] = dinv[row] * (x[row,:] @ W1)
__global__ __launch_bounds__(256) void k_gemm0(const float* __restrict__ S,
                                               const float* __restrict__ W0,
                                               const float* __restrict__ b0,
                                               const u16* __restrict__ Wt,
                                               const float* __restrict__ dinv,
                                               u16* __restrict__ q, int nrows) {
    __shared__ u16 Wl[HID * HID];  // 32 KiB
    __shared__ float w0s[HID], b0s[HID];
    int tid = threadIdx.x;
    if (tid < HID) { w0s[tid] = W0[tid]; b0s[tid] = b0[tid]; }
    for (int i = tid; i < 2048; i += 256)
        *(uint4*)&Wl[i * 8] = *(const uint4*)&Wt[i * 8];

    int w = tid >> 6;
    int l = tid & 63;
    int R0 = blockIdx.x * 64 + w * 16;
    int arow = R0 + (l & 15);
    int koff = (l >> 4) * 8;
    float s = (arow < nrows) ? S[arow] : 0.0f;
    __syncthreads();

    short8 a[4];
#pragma unroll
    for (int kb = 0; kb < 4; ++kb) {
        if (arow < nrows) {
#pragma unroll
            for (int j = 0; j < 8; ++j) {
                int k = kb * 32 + koff + j;
                float val = fmaxf(fmaf(s, w0s[k], b0s[k]), 0.0f);
                a[kb][j] = (short)f2bf(val);
            }
        } else {
            a[kb] = (short8)0;
        }
    }

    int colbase = l & 15;
    int rowq = (l >> 4) * 4;
    float dv[4];
#pragma unroll
    for (int i = 0; i < 4; ++i) {
        int orow = R0 + rowq + i;
        dv[i] = (orow < nrows) ? dinv[orow] : 0.0f;
    }
#pragma unroll
    for (int cb = 0; cb < 8; ++cb) {
        f32x4 acc = {0.0f, 0.0f, 0.0f, 0.0f};
        int wrow = cb * 16 + (l & 15);
#pragma unroll
        for (int kb = 0; kb < 4; ++kb) {
            int j = (kb * 4 + (l >> 4)) ^ (wrow & 7);
            short8 b = *(const short8*)&Wl[wrow * HID + j * 8];
            acc = __builtin_amdgcn_mfma_f32_16x16x32_bf16(a[kb], b, acc, 0, 0, 0);
        }
#pragma unroll
        for (int i = 0; i < 4; ++i) {
            int orow = R0 + rowq + i;
            if (orow < nrows)
                q[(size_t)orow * HID + cb * 16 + colbase] = f2bf(acc[i] * dv[i]);
        }
    }
}

// ---------- MFMA GEMM (layer 2) with dinv-premultiplied output ----------
__global__ __launch_bounds__(256) void k_gemm(const u16* __restrict__ x,
                                              const u16* __restrict__ Wt,
                                              const float* __restrict__ dinv,
                                              u16* __restrict__ q, int nrows) {
    __shared__ u16 Wl[HID * HID];  // 32 KiB
    int tid = threadIdx.x;
    for (int i = tid; i < 2048; i += 256)
        *(uint4*)&Wl[i * 8] = *(const uint4*)&Wt[i * 8];

    int w = tid >> 6;
    int l = tid & 63;
    int R0 = blockIdx.x * 64 + w * 16;
    int arow = R0 + (l & 15);
    int koff = (l >> 4) * 8;

    short8 a[4];
#pragma unroll
    for (int kb = 0; kb < 4; ++kb) {
        if (arow < nrows)
            a[kb] = *(const short8*)&x[(size_t)arow * HID + kb * 32 + koff];
        else
            a[kb] = (short8)0;
    }
    __syncthreads();

    int colbase = l & 15;
    int rowq = (l >> 4) * 4;
    float dv[4];
#pragma unroll
    for (int i = 0; i < 4; ++i) {
        int orow = R0 + rowq + i;
        dv[i] = (orow < nrows) ? dinv[orow] : 0.0f;
    }
#pragma unroll
    for (int cb = 0; cb < 8; ++cb) {
        f32x4 acc = {0.0f, 0.0f, 0.0f, 0.0f};
        int wrow = cb * 16 + (l & 15);
#pragma unroll
        for (int kb = 0; kb < 4; ++kb) {
            int j = (kb * 4 + (l >> 4)) ^ (wrow & 7);
            short8 b = *(const short8*)&Wl[wrow * HID + j * 8];
            acc = __builtin_amdgcn_mfma_f32_16x16x32_bf16(a[kb], b, acc, 0, 0, 0);
        }
#pragma unroll
        for (int i = 0; i < 4; ++i) {
            int orow = R0 + rowq + i;
            if (orow < nrows)
                q[(size_t)orow * HID + cb * 16 + colbase] = f2bf(acc[i] * dv[i]);
        }
    }
}

// ---------- fused aggregation (unweighted q-sum, 2x-unrolled gather; 32-lane group) ----------
// y[v,:] = relu( dinv[v]*(q[v,:] + sum_e q[src_e,:]) + b )
__global__ __launch_bounds__(256) void k_aggr(const u32* __restrict__ packed,
                                              const int* __restrict__ rowptr,
                                              const u16* __restrict__ q,
                                              const float* __restrict__ dinv,
                                              const float* __restrict__ b,
                                              u16* __restrict__ y, int N) {
    int lane = threadIdx.x & 31;
    int v = (blockIdx.x * 256 + threadIdx.x) >> 5;
    if (v >= N) return;
    int r0 = rowptr[v], r1 = rowptr[v + 1];
    int half = lane >> 4;
    int d8 = (lane & 15) * 8;

    float acc[8];
    if (half == 0) {
        uint4 qv = *(const uint4*)&q[(size_t)v * HID + d8];
        bf8_unpack(qv, acc);
    } else {
#pragma unroll
        for (int j = 0; j < 8; ++j) acc[j] = 0.0f;
    }

    for (int base = r0; base < r1; base += 32) {
        int idx = base + lane;
        u32 e = (idx < r1) ? packed[idx] : NOEDGE;
        int m = r1 - base; if (m > 32) m = 32;
        int iters = (m + 1) >> 1;   // k-steps; step k covers edges 2k / 2k+1
        int k = 0;
        for (; k + 2 <= iters; k += 2) {
            u32 s0 = __shfl(e, 2 * k + half, 32);
            u32 s1 = __shfl(e, 2 * k + 2 + half, 32);
            uint4 h0 = make_uint4(0, 0, 0, 0);
            uint4 h1 = make_uint4(0, 0, 0, 0);
            if (s0 != NOEDGE) h0 = *(const uint4*)&q[(size_t)s0 * HID + d8];
            if (s1 != NOEDGE) h1 = *(const uint4*)&q[(size_t)s1 * HID + d8];
            float f0[8], f1[8];
            bf8_unpack(h0, f0);
            bf8_unpack(h1, f1);
#pragma unroll
            for (int j = 0; j < 8; ++j) acc[j] += f0[j] + f1[j];
        }
        if (k < iters) {
            u32 s0 = __shfl(e, 2 * k + half, 32);
            if (s0 != NOEDGE) {
                uint4 h0 = *(const uint4*)&q[(size_t)s0 * HID + d8];
                float f0[8];
                bf8_unpack(h0, f0);
#pragma unroll
                for (int j = 0; j < 8; ++j) acc[j] += f0[j];
            }
        }
    }
#pragma unroll
    for (int j = 0; j < 8; ++j) acc[j] += __shfl_xor(acc[j], 16, 32);

    if (half == 0) {
        float dv = dinv[v];
        float4 b0 = *(const float4*)&b[d8];
        float4 b1 = *(const float4*)&b[d8 + 4];
        float o[8];
        o[0] = fmaxf(fmaf(acc[0], dv, b0.x), 0.0f);
        o[1] = fmaxf(fmaf(acc[1], dv, b0.y), 0.0f);
        o[2] = fmaxf(fmaf(acc[2], dv, b0.z), 0.0f);
        o[3] = fmaxf(fmaf(acc[3], dv, b0.w), 0.0f);
        o[4] = fmaxf(fmaf(acc[4], dv, b1.x), 0.0f);
        o[5] = fmaxf(fmaf(acc[5], dv, b1.y), 0.0f);
        o[6] = fmaxf(fmaf(acc[6], dv, b1.z), 0.0f);
        o[7] = fmaxf(fmaf(acc[7], dv, b1.w), 0.0f);
        uint4 u;
        u.x = (u32)f2bf(o[0]) | ((u32)f2bf(o[1]) << 16);
        u.y = (u32)f2bf(o[2]) | ((u32)f2bf(o[3]) << 16);
        u.z = (u32)f2bf(o[4]) | ((u32)f2bf(o[5]) << 16);
        u.w = (u32)f2bf(o[6]) | ((u32)f2bf(o[7]) << 16);
        *(uint4*)&y[(size_t)v * HID + d8] = u;
    }
}

// ---------- pooling (16 lanes x 8 dims per node) ----------
__global__ __launch_bounds__(256) void k_pool(const u16* __restrict__ x,
                                              const int* __restrict__ batch,
                                              float* __restrict__ pooled,
                                              float* __restrict__ cntg, int N) {
    const int K = 32;
    int grp = threadIdx.x >> 4;
    int lane16 = threadIdx.x & 15;
    int d8 = lane16 * 8;
    int chunk = blockIdx.x * 16 + grp;
    int v0 = chunk * K;
    if (v0 >= N) return;
    int vend = v0 + K; if (vend > N) vend = N;
    int g = batch[v0];
    float acc[8] = {0, 0, 0, 0, 0, 0, 0, 0};
    float c = 0.0f;
    for (int v = v0; v < vend; ++v) {
        int gv = batch[v];
        if (gv != g) {
#pragma unroll
            for (int j = 0; j < 8; ++j) atomicAdd(&pooled[g * HID + d8 + j], acc[j]);
            if (lane16 == 0) atomicAdd(&cntg[g], c);
#pragma unroll
            for (int j = 0; j < 8; ++j) acc[j] = 0.0f;
            c = 0.0f; g = gv;
        }
        uint4 u = *(const uint4*)&x[(size_t)v * HID + d8];
        float f[8];
        bf8_unpack(u, f);
#pragma unroll
        for (int j = 0; j < 8; ++j) acc[j] += f[j];
        c += 1.0f;
    }
#pragma unroll
    for (int j = 0; j < 8; ++j) atomicAdd(&pooled[g * HID + d8 + j], acc[j]);
    if (lane16 == 0) atomicAdd(&cntg[g], c);
}

__global__ void k_head(const float* __restrict__ pooled, const float* __restrict__ cnt,
                       const float* __restrict__ Wp, const float* __restrict__ bp,
                       float* __restrict__ out) {
    int g = gtid();
    if (g >= NG) return;
    float inv = 1.0f / fmaxf(cnt[g], 1.0f);
    float l[NC];
#pragma unroll
    for (int c = 0; c < NC; ++c) l[c] = bp[c];
    for (int d = 0; d < HID; ++d) {
        float pv = pooled[g * HID + d] * inv;
#pragma unroll
        for (int c = 0; c < NC; ++c) l[c] = fmaf(pv, Wp[d * NC + c], l[c]);
    }
    float m = l[0];
#pragma unroll
    for (int c = 1; c < NC; ++c) m = fmaxf(m, l[c]);
    float s = 0.0f;
#pragma unroll
    for (int c = 0; c < NC; ++c) s += expf(l[c] - m);
    float ls = logf(s) + m;
#pragma unroll
    for (int c = 0; c < NC; ++c) out[g * NC + c] = l[c] - ls;
}

extern "C" void kernel_launch(void* const* d_in, const int* in_sizes, int n_in,
                              void* d_out, int out_size, void* d_ws, size_t ws_size,
                              hipStream_t stream) {
    const int* ei    = (const int*)d_in[0];
    int E            = in_sizes[0] / 2;
    const int* src   = ei;
    const int* dstp  = ei + E;
    const int* batch = (const int*)d_in[1];
    int N            = in_sizes[1];
    const float* W0  = (const float*)d_in[2];
    const float* b0  = (const float*)d_in[3];
    const float* W1  = (const float*)d_in[4];
    const float* b1  = (const float*)d_in[5];
    const float* W2  = (const float*)d_in[6];
    const float* b2  = (const float*)d_in[7];
    const float* Wp  = (const float*)d_in[8];
    const float* bp  = (const float*)d_in[9];
    float* out       = (float*)d_out;

    // workspace layout
    u16*  xA     = (u16*)d_ws;                    // N*HID bf16
    u16*  xB     = xA + (size_t)N * HID;          // N*HID bf16
    u32*  packed = (u32*)(xB + (size_t)N * HID);  // E u32 (src per CSR slot)
    u32*  tmp    = packed + E;                    // E u32 (bucket-partitioned (src<<9)|dl)
    u16*  Wt1    = (u16*)(tmp + E);               // 128*128 bf16
    u16*  Wt2    = Wt1 + HID * HID;               // 128*128 bf16
    int*  rowptr = (int*)(Wt2 + HID * HID);       // N+1
    int*  bcnt   = rowptr + N + 1;                // 256
    int*  bbase  = bcnt + 256;                    // 257
    int*  bcur   = bbase + 257;                   // 256
    float* S     = (float*)(bcur + 256);          // N
    float* dinv  = S + N;                         // N
    float* pooled= dinv + N;                      // NG*HID
    float* cntg  = pooled + NG * HID;             // NG

    auto cdiv = [](int a, int b) { return (a + b - 1) / b; };
    int NB = cdiv(N, BSZ);                        // 196 buckets

    hipMemsetAsync(bcnt, 0, 256 * sizeof(int), stream);
    hipMemsetAsync(pooled, 0, (NG * HID + NG) * sizeof(float), stream);

    // CSR build
    k_bhist<<<cdiv(E, TILE), 256, 0, stream>>>(dstp, bcnt, E, NB);
    k_bscan<<<1, 256, 0, stream>>>(bcnt, bbase, bcur, NB, E);
    k_part1<<<cdiv(E, TILE), 256, 0, stream>>>(src, dstp, bcur, tmp, E, NB);
    k_part2<<<NB, 512, 0, stream>>>(bbase, tmp, packed, rowptr, dinv, N, NB);

    // weight prep + per-node scalar S
    k_wt<<<8, 256, 0, stream>>>(W1, Wt1);
    k_wt<<<8, 256, 0, stream>>>(W2, Wt2);
    k_S<<<cdiv(N, 8), 256, 0, stream>>>(rowptr, packed, dinv, S, N);

    // layer 1: fused layer0 + GEMM1 -> xB; aggregation -> xA
    k_gemm0<<<cdiv(N, 64), 256, 0, stream>>>(S, W0, b0, Wt1, dinv, xB, N);
    k_aggr<<<cdiv(N, 8), 256, 0, stream>>>(packed, rowptr, xB, dinv, b1, xA, N);

    // layer 2: GEMM + aggregation
    k_gemm<<<cdiv(N, 64), 256, 0, stream>>>(xA, Wt2, dinv, xB, N);
    k_aggr<<<cdiv(N, 8), 256, 0, stream>>>(packed, rowptr, xB, dinv, b2, xA, N);

    // pooling + head
    k_pool<<<cdiv(cdiv(N, 32), 16), 256, 0, stream>>>(xA, batch, pooled, cntg, N);
    k_head<<<2, 256, 0, stream>>>(pooled, cntg, Wp, bp, out);
}